// Round 7
// baseline (117.459 us; speedup 1.0000x reference)
//
#include <hip/hip_runtime.h>

#define KK 3
#define BB 64
#define VV 128000
#define HH 7168
#define MAXR 128
#define NROWS (BB * (KK + 1) + BB * KK)  // 448 argmax rows
#define SEG 25                           // fine segments per row
#define NSEG (NROWS * SEG)               // 11200 segments, 1280 f4 each
#define NBLK 2048                        // exactly 8 blocks/CU on 256 CUs
#define BIGB (NSEG - NBLK * (NSEG / NBLK))  // 960 blocks take +1 segment

typedef float f4 __attribute__((ext_vector_type(4)));

// Output layout (all float32, concatenated flat in return order):
//  0: logits               [BB*(KK+1), VV]
//  1: accepted_tokens      [BB, KK+1]
//  2: num_accepted         [BB]
//  3: next_draft_tokens    [BB, KK]
//  4: next_new_tokens      [BB, KK+1]
//  5: new_hidden_pool      [MAXR, KK, HH]
//  6: new_tokens_pool      [MAXR, KK]
static constexpr size_t OFF_ACC = (size_t)BB * (KK + 1) * VV;
static constexpr size_t OFF_NUM = OFF_ACC + (size_t)BB * (KK + 1);
static constexpr size_t OFF_ND  = OFF_NUM + BB;
static constexpr size_t OFF_NN  = OFF_ND + (size_t)BB * KK;
static constexpr size_t OFF_HP  = OFF_NN + (size_t)BB * (KK + 1);
static constexpr size_t OFF_TP  = OFF_HP + (size_t)MAXR * KK * HH;

__device__ __forceinline__ void scan4(const f4& v, int base, float& best, int& bidx) {
    // increasing-index visit order -> strict '>' keeps first occurrence
    if (v.x > best) { best = v.x; bidx = base; }
    if (v.y > best) { best = v.y; bidx = base + 1; }
    if (v.z > best) { best = v.z; bidx = base + 2; }
    if (v.w > best) { best = v.w; bidx = base + 3; }
}

// ---------------------------------------------------------------------------
// Kernel 1: barrier-free partial argmax + pass-through copy.
// Grid = 2048 blocks (8/CU exact). Segment s (0..11199): row = s/25,
// sub = s%25, covers f4 [sub*1280, +1280) of that row; each thread does one
// 5-load cluster. Blocks 0..959 process 6 segments, 960..2047 process 5 —
// the last round still has 960 live blocks so HBM stays saturated (no tail).
// Per-WAVE partials (4 per segment) go straight to ws: no LDS, no barrier.
// ---------------------------------------------------------------------------
__global__ __launch_bounds__(256) void argmax_partial_copy_kernel(
    const float* __restrict__ logits,        // [256, VV]
    const float* __restrict__ draft_logits,  // [192, VV]
    float* __restrict__ out_logits,          // d_out
    int* __restrict__ ws_pidx,               // [NSEG*4]
    float* __restrict__ ws_pval)             // [NSEG*4]
{
    const int b   = blockIdx.x;
    const int tid = threadIdx.x;
    const int nseg_mine = (b < BIGB) ? (NSEG / NBLK + 1) : (NSEG / NBLK);
    const int seg0 = (b < BIGB) ? b * (NSEG / NBLK + 1)
                                : BIGB * (NSEG / NBLK + 1) + (b - BIGB) * (NSEG / NBLK);

    for (int s = seg0; s < seg0 + nseg_mine; ++s) {
        const int row = (unsigned)s / SEG;
        const int sub = s - row * SEG;
        const bool is_target = (row < BB * (KK + 1));

        const float* srcf = is_target
            ? (logits + (size_t)row * VV)
            : (draft_logits + (size_t)(row - BB * (KK + 1)) * VV);
        const f4* src4 = reinterpret_cast<const f4*>(srcf);
        f4* dst4 = reinterpret_cast<f4*>(out_logits + (size_t)row * VV);

        const int i0 = sub * 1280 + tid;
        f4 v0 = src4[i0];
        f4 v1 = src4[i0 + 256];
        f4 v2 = src4[i0 + 512];
        f4 v3 = src4[i0 + 768];
        f4 v4 = src4[i0 + 1024];
        __builtin_amdgcn_sched_barrier(0);  // keep the 5-load cluster together
        float best = -__builtin_huge_valf();
        int bidx = 0;
        scan4(v0, i0 * 4, best, bidx);
        scan4(v1, (i0 + 256) * 4, best, bidx);
        scan4(v2, (i0 + 512) * 4, best, bidx);
        scan4(v3, (i0 + 768) * 4, best, bidx);
        scan4(v4, (i0 + 1024) * 4, best, bidx);
        if (is_target) {
            __builtin_nontemporal_store(v0, dst4 + i0);
            __builtin_nontemporal_store(v1, dst4 + i0 + 256);
            __builtin_nontemporal_store(v2, dst4 + i0 + 512);
            __builtin_nontemporal_store(v3, dst4 + i0 + 768);
            __builtin_nontemporal_store(v4, dst4 + i0 + 1024);
        }

        // wave-level (val,idx) butterfly; tiebreak by smaller index
        #pragma unroll
        for (int off = 32; off > 0; off >>= 1) {
            const float ov = __shfl_xor(best, off, 64);
            const int   oi = __shfl_xor(bidx, off, 64);
            if (ov > best || (ov == best && oi < bidx)) { best = ov; bidx = oi; }
        }
        if ((tid & 63) == 0) {
            const int p = s * 4 + (tid >> 6);   // = row*100 + sub*4 + wave
            ws_pidx[p] = bidx;
            ws_pval[p] = best;
        }
    }
}

// ---------------------------------------------------------------------------
// Kernel 2: reduce 100 per-wave partials per row + all small logic.
// One block, 512 threads (448 active for the reduce).
// ---------------------------------------------------------------------------
__global__ __launch_bounds__(512) void logic_kernel(
    const int* __restrict__ draft_tokens,      // [BB, KK]
    const int* __restrict__ slot_ids,          // [BB]
    const int* __restrict__ past_tokens_pool,  // [MAXR, KK]
    const int* __restrict__ ws_pidx,           // [NSEG*4]
    const float* __restrict__ ws_pval,         // [NSEG*4]
    float* __restrict__ out,                   // d_out base (float32)
    int* __restrict__ ws_numacc,               // [BB]
    int* __restrict__ ws_inv)                  // [MAXR]
{
    __shared__ int s_am[NROWS];
    __shared__ int s_numacc[BB];
    __shared__ int s_inv[MAXR];

    const int tid = threadIdx.x;

    if (tid < NROWS) {
        const int base = tid * SEG * 4;        // 100 partials per row
        float best = ws_pval[base];
        int bidx = ws_pidx[base];
        for (int j = 1; j < SEG * 4; ++j) {
            const float v = ws_pval[base + j];
            const int   i = ws_pidx[base + j];
            if (v > best || (v == best && i < bidx)) { best = v; bidx = i; }
        }
        s_am[tid] = bidx;
    }
    if (tid < MAXR) s_inv[tid] = -1;
    __syncthreads();
    if (tid < BB) s_inv[slot_ids[tid]] = tid;  // unique slots per harness input

    if (tid < BB) {
        int t[KK + 1];
        #pragma unroll
        for (int k = 0; k <= KK; ++k) t[k] = s_am[tid * (KK + 1) + k];

        int na = 1;
        #pragma unroll
        for (int k = 0; k < KK; ++k) {
            if (t[k] == draft_tokens[tid * KK + k] && na == k + 1) na++;
        }
        s_numacc[tid] = na;
        ws_numacc[tid] = na;

        #pragma unroll
        for (int k = 0; k <= KK; ++k)
            out[OFF_ACC + tid * (KK + 1) + k] = (float)t[k];
        out[OFF_NUM + tid] = (float)na;

        int nd[KK];
        #pragma unroll
        for (int k = 0; k < KK; ++k) {
            nd[k] = s_am[BB * (KK + 1) + tid * KK + k];
            out[OFF_ND + tid * KK + k] = (float)nd[k];
        }
        out[OFF_NN + tid * (KK + 1)] = (float)t[na - 1];
        #pragma unroll
        for (int k = 0; k < KK; ++k)
            out[OFF_NN + tid * (KK + 1) + 1 + k] = (float)nd[k];
    }
    __syncthreads();

    if (tid < MAXR) {
        const int b = s_inv[tid];
        ws_inv[tid] = b;
        if (b < 0) {
            #pragma unroll
            for (int k = 0; k < KK; ++k)
                out[OFF_TP + tid * KK + k] = (float)past_tokens_pool[tid * KK + k];
        } else {
            const int na = s_numacc[b];
            #pragma unroll
            for (int k = 0; k < KK; ++k) {
                const int src = na + k;  // in [1, 2*KK]
                const int v = (src < KK)
                    ? past_tokens_pool[tid * KK + src]
                    : s_am[b * (KK + 1) + (src - KK)];
                out[OFF_TP + tid * KK + k] = (float)v;
            }
        }
    }
}

// ---------------------------------------------------------------------------
// Kernel 3: new_hidden_pool. 4 blocks per pool row; non-temporal stores.
// ---------------------------------------------------------------------------
#define HSPLIT 4
__global__ __launch_bounds__(256) void hidden_pool_kernel(
    const float* __restrict__ hidden_states,     // [BB*(KK+1), HH]
    const float* __restrict__ past_hidden_pool,  // [MAXR, KK, HH]
    const int* __restrict__ ws_numacc,           // [BB]
    const int* __restrict__ ws_inv,              // [MAXR]
    float* __restrict__ out_hp)                  // d_out + OFF_HP
{
    const int rowid = blockIdx.x / HSPLIT;  // slot * KK + k
    const int q     = blockIdx.x % HSPLIT;
    const int slot = rowid / KK;
    const int k = rowid - slot * KK;
    const int b = ws_inv[slot];

    const float* src;
    if (b < 0) {
        src = past_hidden_pool + (size_t)rowid * HH;
    } else {
        const int srcrow = ws_numacc[b] + k;  // in [1, 2*KK]
        src = (srcrow < KK)
            ? past_hidden_pool + ((size_t)slot * KK + srcrow) * HH
            : hidden_states + ((size_t)b * (KK + 1) + (srcrow - KK)) * HH;
    }

    const f4* s4 = reinterpret_cast<const f4*>(src);
    f4* d4 = reinterpret_cast<f4*>(out_hp + (size_t)rowid * HH);
    const int n4 = HH / 4;                    // 1792
    const int per = n4 / HSPLIT;              // 448
    const int lo = q * per;
    for (int i = lo + threadIdx.x; i < lo + per; i += 256) {
        f4 v = s4[i];
        __builtin_nontemporal_store(v, d4 + i);
    }
}

extern "C" void kernel_launch(void* const* d_in, const int* in_sizes, int n_in,
                              void* d_out, int out_size, void* d_ws, size_t ws_size,
                              hipStream_t stream) {
    const float* logits           = (const float*)d_in[0];
    const float* hidden_states    = (const float*)d_in[1];
    const int*   draft_tokens     = (const int*)d_in[2];
    const int*   slot_ids         = (const int*)d_in[3];
    const float* past_hidden_pool = (const float*)d_in[4];
    const int*   past_tokens_pool = (const int*)d_in[5];
    const float* draft_logits     = (const float*)d_in[6];

    float* out = (float*)d_out;

    int* wsI = (int*)d_ws;
    int*   ws_pidx   = wsI;                           // NSEG*4 = 44800
    float* ws_pval   = (float*)(wsI + NSEG * 4);      // 44800
    int*   ws_numacc = wsI + 2 * NSEG * 4;            // 64
    int*   ws_inv    = ws_numacc + BB;                // 128

    argmax_partial_copy_kernel<<<NBLK, 256, 0, stream>>>(
        logits, draft_logits, out, ws_pidx, ws_pval);

    logic_kernel<<<1, 512, 0, stream>>>(
        draft_tokens, slot_ids, past_tokens_pool, ws_pidx, ws_pval,
        out, ws_numacc, ws_inv);

    hidden_pool_kernel<<<MAXR * KK * HSPLIT, 256, 0, stream>>>(
        hidden_states, past_hidden_pool, ws_numacc, ws_inv, out + OFF_HP);
}

// Round 8
// 66.415 us; speedup vs baseline: 1.7686x; 1.7686x over previous
//
#include <hip/hip_runtime.h>

#define KK 3
#define BB 64
#define VV 128000
#define HH 7168
#define MAXR 128
#define NROWS (BB * (KK + 1) + BB * KK)  // 448 argmax rows
#define SEG 5                            // blocks per row
#define UNROLL 5                         // independent loads per iteration
#define HSPLIT 4
#define NPOOLBLK (MAXR * KK * HSPLIT)    // 1536 hidden-pool blocks

typedef float f4 __attribute__((ext_vector_type(4)));

// Output layout (all float32, concatenated flat in return order):
//  0: logits               [BB*(KK+1), VV]
//  1: accepted_tokens      [BB, KK+1]
//  2: num_accepted         [BB]
//  3: next_draft_tokens    [BB, KK]
//  4: next_new_tokens      [BB, KK+1]
//  5: new_hidden_pool      [MAXR, KK, HH]
//  6: new_tokens_pool      [MAXR, KK]
static constexpr size_t OFF_ACC = (size_t)BB * (KK + 1) * VV;
static constexpr size_t OFF_NUM = OFF_ACC + (size_t)BB * (KK + 1);
static constexpr size_t OFF_ND  = OFF_NUM + BB;
static constexpr size_t OFF_NN  = OFF_ND + (size_t)BB * KK;
static constexpr size_t OFF_HP  = OFF_NN + (size_t)BB * (KK + 1);
static constexpr size_t OFF_TP  = OFF_HP + (size_t)MAXR * KK * HH;

__device__ __forceinline__ void scan4(const f4& v, int base, float& best, int& bidx) {
    // increasing-index visit order -> strict '>' keeps first occurrence
    if (v.x > best) { best = v.x; bidx = base; }
    if (v.y > best) { best = v.y; bidx = base + 1; }
    if (v.z > best) { best = v.z; bidx = base + 2; }
    if (v.w > best) { best = v.w; bidx = base + 3; }
}

// (val,idx) max with first-occurrence tiebreak
__device__ __forceinline__ void vimax(float v, int i, float& best, int& bidx) {
    if (v > best || (v == best && i < bidx)) { best = v; bidx = i; }
}

// reduce the SEG=5 per-block partials of one row -> argmax index
__device__ __forceinline__ int row_argmax(const int* ws_pidx, const float* ws_pval, int row) {
    const int base = row * SEG;
    float best = ws_pval[base];
    int bidx = ws_pidx[base];
    #pragma unroll
    for (int s = 1; s < SEG; ++s) vimax(ws_pval[base + s], ws_pidx[base + s], best, bidx);
    return bidx;
}

// ---------------------------------------------------------------------------
// Kernel 1 (identical to R6 best): partial argmax + pass-through copy.
// grid = (SEG=5, NROWS=448). 5 rounds of 5 independent dwordx4 loads,
// sched_barrier pins the cluster, scans, NT stores. One shuffle reduce at
// block end + tiny LDS step; 1 partial per (row,seg).
// ---------------------------------------------------------------------------
__global__ __launch_bounds__(256) void argmax_partial_copy_kernel(
    const float* __restrict__ logits,        // [256, VV]
    const float* __restrict__ draft_logits,  // [192, VV]
    float* __restrict__ out_logits,          // d_out
    int* __restrict__ ws_pidx,               // [NROWS*SEG]
    float* __restrict__ ws_pval)             // [NROWS*SEG]
{
    const int seg = blockIdx.x;
    const int row = blockIdx.y;
    const int tid = threadIdx.x;
    const bool is_target = (row < BB * (KK + 1));

    const float* srcf = is_target ? (logits + (size_t)row * VV)
                                  : (draft_logits + (size_t)(row - BB * (KK + 1)) * VV);
    const f4* src4 = reinterpret_cast<const f4*>(srcf);
    f4* dst4 = is_target
        ? reinterpret_cast<f4*>(out_logits + (size_t)row * VV)
        : nullptr;

    float best = -__builtin_huge_valf();
    int bidx = 0;
    // 32000 float4/row = SEG(5) * ITERS(5) * UNROLL(5) * 256
    const int base = seg * 6400;

    #pragma unroll 1
    for (int it = 0; it < 5; ++it) {
        const int i0 = base + it * (UNROLL * 256) + tid;
        f4 v0 = src4[i0];
        f4 v1 = src4[i0 + 256];
        f4 v2 = src4[i0 + 512];
        f4 v3 = src4[i0 + 768];
        f4 v4 = src4[i0 + 1024];
        __builtin_amdgcn_sched_barrier(0);  // pin: all 5 loads issued first
        scan4(v0, i0 * 4, best, bidx);
        scan4(v1, (i0 + 256) * 4, best, bidx);
        scan4(v2, (i0 + 512) * 4, best, bidx);
        scan4(v3, (i0 + 768) * 4, best, bidx);
        scan4(v4, (i0 + 1024) * 4, best, bidx);
        if (is_target) {
            __builtin_nontemporal_store(v0, dst4 + i0);
            __builtin_nontemporal_store(v1, dst4 + i0 + 256);
            __builtin_nontemporal_store(v2, dst4 + i0 + 512);
            __builtin_nontemporal_store(v3, dst4 + i0 + 768);
            __builtin_nontemporal_store(v4, dst4 + i0 + 1024);
        }
    }

    // wave-level (val,idx) butterfly; tiebreak by smaller index
    #pragma unroll
    for (int off = 32; off > 0; off >>= 1) {
        const float ov = __shfl_xor(best, off, 64);
        const int   oi = __shfl_xor(bidx, off, 64);
        vimax(ov, oi, best, bidx);
    }

    __shared__ float swv[4];
    __shared__ int   swi[4];
    if ((tid & 63) == 0) { swv[tid >> 6] = best; swi[tid >> 6] = bidx; }
    __syncthreads();
    if (tid == 0) {
        #pragma unroll
        for (int w = 1; w < 4; ++w) vimax(swv[w], swi[w], best, bidx);
        ws_pidx[row * SEG + seg] = bidx;
        ws_pval[row * SEG + seg] = best;
    }
}

// ---------------------------------------------------------------------------
// Kernel 2 (merged pool + logic): grid = NPOOLBLK + 1 blocks, 256 threads.
// Blocks [0, NPOOLBLK): hidden-pool copy. Each block re-derives its slot's
//   batch index b (wave-0 ballot over 64 slot_ids) and num_accepted (reduce
//   4 target rows x 5 partials) locally — no dependency on a logic kernel.
//   q==0 blocks also write their slot's 3 token-pool entries.
// Block NPOOLBLK: writes the small token outputs (ACC/NUM/ND/NN).
// ---------------------------------------------------------------------------
__global__ __launch_bounds__(256) void pool_logic_kernel(
    const float* __restrict__ hidden_states,     // [BB*(KK+1), HH]
    const float* __restrict__ past_hidden_pool,  // [MAXR, KK, HH]
    const int* __restrict__ draft_tokens,        // [BB, KK]
    const int* __restrict__ slot_ids,            // [BB]
    const int* __restrict__ past_tokens_pool,    // [MAXR, KK]
    const int* __restrict__ ws_pidx,             // [NROWS*SEG]
    const float* __restrict__ ws_pval,           // [NROWS*SEG]
    float* __restrict__ out)                     // d_out base
{
    const int tid = threadIdx.x;

    if (blockIdx.x == NPOOLBLK) {
        // ---- logic block: small token outputs ----
        __shared__ int s_t[BB * (KK + 1)];  // target tokens, 256
        __shared__ int s_d[BB * KK];        // draft argmax tokens, 192

        s_t[tid] = row_argmax(ws_pidx, ws_pval, tid);              // rows 0..255
        if (tid < BB * KK)
            s_d[tid] = row_argmax(ws_pidx, ws_pval, BB * (KK + 1) + tid);
        __syncthreads();

        if (tid < BB) {
            int t[KK + 1];
            #pragma unroll
            for (int k = 0; k <= KK; ++k) t[k] = s_t[tid * (KK + 1) + k];

            int na = 1;
            #pragma unroll
            for (int k = 0; k < KK; ++k)
                if (t[k] == draft_tokens[tid * KK + k] && na == k + 1) na++;

            #pragma unroll
            for (int k = 0; k <= KK; ++k)
                out[OFF_ACC + tid * (KK + 1) + k] = (float)t[k];
            out[OFF_NUM + tid] = (float)na;

            int nd[KK];
            #pragma unroll
            for (int k = 0; k < KK; ++k) {
                nd[k] = s_d[tid * KK + k];
                out[OFF_ND + tid * KK + k] = (float)nd[k];
            }
            out[OFF_NN + tid * (KK + 1)] = (float)t[na - 1];
            #pragma unroll
            for (int k = 0; k < KK; ++k)
                out[OFF_NN + tid * (KK + 1) + 1 + k] = (float)nd[k];
        }
        return;
    }

    // ---- hidden-pool block ----
    const int rowid = blockIdx.x / HSPLIT;  // slot * KK + k
    const int q     = blockIdx.x % HSPLIT;
    const int slot  = rowid / KK;
    const int k     = rowid - slot * KK;

    __shared__ int s_b, s_na, s_tok[KK + 1];

    // wave 0: find b with ballot, then 4 lanes reduce the 4 target rows
    if (tid < 64) {
        const bool hit = (slot_ids[tid] == slot);
        const unsigned long long m = __ballot(hit);
        const int b = (int)__ffsll((long long)m) - 1;   // -1 if no match
        if (tid == 0) s_b = b;
        if (b >= 0) {
            if (tid < KK + 1)
                s_tok[tid] = row_argmax(ws_pidx, ws_pval, b * (KK + 1) + tid);
            // lane 0 computes na after lanes 0..3 wrote s_tok (same wave,
            // but LDS writes need a wave-internal guarantee: use shuffle
            // instead — each lane tid<4 broadcasts its token via shfl.
        }
    }
    __syncthreads();

    const int b = s_b;
    int na = 1;
    if (b >= 0 && tid == 0) {
        #pragma unroll
        for (int kk2 = 0; kk2 < KK; ++kk2)
            if (s_tok[kk2] == draft_tokens[b * KK + kk2] && na == kk2 + 1) na++;
        s_na = na;
    }
    __syncthreads();

    const float* src;
    if (b < 0) {
        src = past_hidden_pool + (size_t)rowid * HH;
        if (q == 0 && tid < KK)
            out[OFF_TP + rowid + tid - k + k] , // (no-op guard below)
            out[OFF_TP + slot * KK + tid] = (float)past_tokens_pool[slot * KK + tid];
    } else {
        na = s_na;
        const int srcrow = na + k;  // in [1, 2*KK]
        src = (srcrow < KK)
            ? past_hidden_pool + ((size_t)slot * KK + srcrow) * HH
            : hidden_states + ((size_t)b * (KK + 1) + (srcrow - KK)) * HH;
        if (q == 0 && tid < KK) {
            const int sr = na + tid;
            const int v = (sr < KK) ? past_tokens_pool[slot * KK + sr]
                                    : s_tok[sr - KK];
            out[OFF_TP + slot * KK + tid] = (float)v;
        }
    }

    const f4* s4 = reinterpret_cast<const f4*>(src);
    f4* d4 = reinterpret_cast<f4*>(out + OFF_HP + (size_t)rowid * HH);
    const int n4 = HH / 4;                    // 1792
    const int per = n4 / HSPLIT;              // 448
    const int lo = q * per;
    for (int i = lo + tid; i < lo + per; i += 256) {
        f4 v = s4[i];
        __builtin_nontemporal_store(v, d4 + i);
    }
}

extern "C" void kernel_launch(void* const* d_in, const int* in_sizes, int n_in,
                              void* d_out, int out_size, void* d_ws, size_t ws_size,
                              hipStream_t stream) {
    const float* logits           = (const float*)d_in[0];
    const float* hidden_states    = (const float*)d_in[1];
    const int*   draft_tokens     = (const int*)d_in[2];
    const int*   slot_ids         = (const int*)d_in[3];
    const float* past_hidden_pool = (const float*)d_in[4];
    const int*   past_tokens_pool = (const int*)d_in[5];
    const float* draft_logits     = (const float*)d_in[6];

    float* out = (float*)d_out;

    int* wsI = (int*)d_ws;
    int*   ws_pidx = wsI;                          // NROWS*SEG = 2240
    float* ws_pval = (float*)(wsI + NROWS * SEG);  // 2240

    dim3 grid1(SEG, NROWS);
    argmax_partial_copy_kernel<<<grid1, 256, 0, stream>>>(
        logits, draft_logits, out, ws_pidx, ws_pval);

    pool_logic_kernel<<<NPOOLBLK + 1, 256, 0, stream>>>(
        hidden_states, past_hidden_pool, draft_tokens, slot_ids,
        past_tokens_pool, ws_pidx, ws_pval, out);
}